// Round 15
// baseline (3403.959 us; speedup 1.0000x reference)
//
#include <hip/hip_runtime.h>
#include <cstdint>
#include <cstddef>

#define TOK 4096      // B*S
#define HD_ 64
#define NH_ 12
#define H_ 768
#define F_ 2048
#define V_ 128
#define L_ 12
#define SEQ 512
#define BQKV (3*H_)
#define BATCH 8

typedef _Float16 f16;
typedef _Float16 f16x8 __attribute__((ext_vector_type(8)));
typedef _Float16 f16x4 __attribute__((ext_vector_type(4)));
typedef float    f32x4 __attribute__((ext_vector_type(4)));

#define GLDS16(g, l) __builtin_amdgcn_global_load_lds( \
    (const __attribute__((address_space(1))) uint32_t*)(g), \
    (__attribute__((address_space(3))) uint32_t*)(l), 16, 0, 0)

__device__ __forceinline__ float wave_sum(float v) {
#pragma unroll
  for (int m = 32; m >= 1; m >>= 1) v += __shfl_xor(v, m);
  return v;
}

__device__ __forceinline__ void split16(float v, f16& h, f16& lo) {
  h = (f16)v;
  lo = (f16)((v - (float)h) * 2048.0f);
}

// XOR-swizzled element index into a [64][64] f16 tile (128B rows)
__device__ __forceinline__ int swz(int r, int c) {
  int byte = (r << 7) + (c << 1);
  byte ^= (r & 7) << 4;
  return byte >> 1;
}

// ---------------- fp32 -> (hi, lo*2^11) f16 planes, optional pre-scale ----------------
__global__ __launch_bounds__(256)
void k_convert(const float* __restrict__ src, f16* __restrict__ h, f16* __restrict__ l,
               int n4, float scale) {
  int i = blockIdx.x * 256 + threadIdx.x;
  int stride = gridDim.x * 256;
  for (; i < n4; i += stride) {
    float4 v = ((const float4*)src)[i];
    v.x *= scale; v.y *= scale; v.z *= scale; v.w *= scale;
    f16x4 vh, vl;
    f16 a, b;
    split16(v.x, a, b); vh[0] = a; vl[0] = b;
    split16(v.y, a, b); vh[1] = a; vl[1] = b;
    split16(v.z, a, b); vh[2] = a; vl[2] = b;
    split16(v.w, a, b); vh[3] = a; vl[3] = b;
    ((f16x4*)h)[i] = vh;
    ((f16x4*)l)[i] = vl;
  }
}

// ---------------- embedding + planes (+ zero route counters) ----------------
__global__ __launch_bounds__(256)
void k_embed2(const int* __restrict__ lid, const int* __restrict__ sid,
              const float* __restrict__ be, const float* __restrict__ se,
              float* __restrict__ x, f16* __restrict__ xh, f16* __restrict__ xl,
              int* __restrict__ counts) {
  int t = blockIdx.x;
  if (t == 0 && threadIdx.x < V_) counts[threadIdx.x] = 0;
  int li = lid[t], si = sid[t];
  const float* bp = be + (size_t)li * H_;
  const float* sp = se + (size_t)si * H_;
  size_t base = (size_t)t * H_;
#pragma unroll
  for (int j = 0; j < 3; ++j) {
    int hh = threadIdx.x + 256 * j;
    float v = bp[hh] + sp[hh];
    x[base + hh] = v;
    f16 a, b; split16(v, a, b);
    xh[base + hh] = a; xl[base + hh] = b;
  }
}

// ---------- split-f16 MFMA GEMM: overlapped reads+MFMA, late STG ----------
// C[M,N] = A[M,K] @ B[N,K]^T. B planes pre-scaled x64.
// acc_hi = Ah.Bh ; acc_mid = Ah.Bl + Al.Bh ; result = (hi + mid/2048)/64.
// MODE 0: fp32 out + bias; 1: relu+planes; 2: planes; 3: fp32 partial (split-K, no bias)
template<int BM, int BN, int MODE, int SPLIT>
__global__ __launch_bounds__(256, 2)
void k_gemm5(const f16* __restrict__ Ah, const f16* __restrict__ Al,
             const f16* __restrict__ Bh, const f16* __restrict__ Bl,
             const float* __restrict__ bias, float* __restrict__ C,
             f16* __restrict__ Ch, f16* __restrict__ Cl,
             int N, int K) {
  constexpr int MI = BM / 32, NJ = BN / 32;
  constexpr int IA = BM / 64, IB = BN / 64;
  constexpr int ABYT = BM * 64, BBYT = BN * 64;
  constexpr int BUFB = 2 * ABYT + 2 * BBYT;
  constexpr int NGL = 2 * (IA + IB);
  __shared__ __align__(16) char sm_[2 * BUFB];
  const int tid = threadIdx.x;
  const int lane = tid & 63, wid = tid >> 6;
  const int wr = wid >> 1, wc = wid & 1;

  // XCD-locality remap (gridDim.x % 8 == 0; pure index permutation)
  const unsigned flat = blockIdx.x + gridDim.x * (blockIdx.y + gridDim.y * blockIdx.z);
  const unsigned G = gridDim.x >> 3;
  const unsigned xcd = flat & 7u;
  const unsigned idx = flat >> 3;
  const unsigned mt = xcd * G + idx % G;
  const unsigned rest = idx / G;
  const unsigned nt = rest % gridDim.y;
  const unsigned zt = rest / gridDim.y;

  const int bm = mt * BM, bn = nt * BN;
  const size_t rs = (size_t)K * 2;
  const size_t koff = (size_t)zt * (size_t)(K / SPLIT) * 2;

  const int srow = tid >> 2, schk = tid & 3;
  const char* ga[2][IA];
  const char* gb[2][IB];
#pragma unroll
  for (int u = 0; u < IA; ++u) {
    int row = u * 64 + srow;
    int c = schk ^ ((row >> 1) & 3);
    ga[0][u] = (const char*)Ah + (size_t)(bm + row) * rs + c * 16 + koff;
    ga[1][u] = (const char*)Al + (size_t)(bm + row) * rs + c * 16 + koff;
  }
#pragma unroll
  for (int u = 0; u < IB; ++u) {
    int row = u * 64 + srow;
    int c = schk ^ ((row >> 1) & 3);
    gb[0][u] = (const char*)Bh + (size_t)(bn + row) * rs + c * 16 + koff;
    gb[1][u] = (const char*)Bl + (size_t)(bn + row) * rs + c * 16 + koff;
  }

  const int rr = lane & 15, cgrp = lane >> 4;
  int aoff[MI][2], boff[NJ][2];
#pragma unroll
  for (int i = 0; i < MI; ++i) {
    int row = wr * (BM / 2) + i * 16 + rr;
    int sw = (cgrp ^ ((row >> 1) & 3)) * 16;
    aoff[i][0] = row * 64 + sw;
    aoff[i][1] = ABYT + row * 64 + sw;
  }
#pragma unroll
  for (int j = 0; j < NJ; ++j) {
    int row = wc * (BN / 2) + j * 16 + rr;
    int sw = (cgrp ^ ((row >> 1) & 3)) * 16;
    boff[j][0] = 2 * ABYT + row * 64 + sw;
    boff[j][1] = 2 * ABYT + BBYT + row * 64 + sw;
  }

  f32x4 aH[MI][NJ], aM[MI][NJ];
#pragma unroll
  for (int i = 0; i < MI; ++i)
#pragma unroll
    for (int j = 0; j < NJ; ++j)
#pragma unroll
      for (int q = 0; q < 4; ++q) { aH[i][j][q] = 0.0f; aM[i][j][q] = 0.0f; }

  auto STG = [&](char* bufbase) __attribute__((always_inline)) {
    char* base = bufbase + wid * 1024;
#pragma unroll
    for (int u = 0; u < IA; ++u) {
      GLDS16(ga[0][u], base + u * 4096);
      GLDS16(ga[1][u], base + ABYT + u * 4096);
      ga[0][u] += 64; ga[1][u] += 64;
    }
#pragma unroll
    for (int u = 0; u < IB; ++u) {
      GLDS16(gb[0][u], base + 2 * ABYT + u * 4096);
      GLDS16(gb[1][u], base + 2 * ABYT + BBYT + u * 4096);
      gb[0][u] += 64; gb[1][u] += 64;
    }
  };

  char* b0 = sm_;
  char* b1 = sm_ + BUFB;
  const int nst = (K / SPLIT) / 32;   // >= 2 for all shapes used
  STG(b0);
  STG(b1);
  for (int s = 0; s < nst; ++s) {
    if (s < nst - 1) {
      asm volatile("s_waitcnt vmcnt(%0)" :: "i"(NGL) : "memory");
    } else {
      asm volatile("s_waitcnt vmcnt(0)" ::: "memory");
    }
    __builtin_amdgcn_s_barrier();
    __builtin_amdgcn_sched_barrier(0);
    const char* base = (s & 1) ? b1 : b0;
    // reads + MFMAs in one region: compiler interleaves with progressive lgkm waits
    f16x8 fb[NJ][2], fa[MI][2];
#pragma unroll
    for (int j = 0; j < NJ; ++j) {
      fb[j][0] = *(const f16x8*)(base + boff[j][0]);
      fb[j][1] = *(const f16x8*)(base + boff[j][1]);
    }
#pragma unroll
    for (int i = 0; i < MI; ++i) {
      fa[i][0] = *(const f16x8*)(base + aoff[i][0]);
      fa[i][1] = *(const f16x8*)(base + aoff[i][1]);
    }
    __builtin_amdgcn_s_setprio(1);
#pragma unroll
    for (int i = 0; i < MI; ++i) {
#pragma unroll
      for (int j = 0; j < NJ; ++j) {
        aH[i][j] = __builtin_amdgcn_mfma_f32_16x16x32_f16(fa[i][0], fb[j][0], aH[i][j], 0, 0, 0);
        aM[i][j] = __builtin_amdgcn_mfma_f32_16x16x32_f16(fa[i][0], fb[j][1], aM[i][j], 0, 0, 0);
        aM[i][j] = __builtin_amdgcn_mfma_f32_16x16x32_f16(fa[i][1], fb[j][0], aM[i][j], 0, 0, 0);
      }
    }
    __builtin_amdgcn_s_setprio(0);
    asm volatile("s_waitcnt lgkmcnt(0)" ::: "memory");
    __builtin_amdgcn_s_barrier();           // all waves consumed buffer s
    __builtin_amdgcn_sched_barrier(0);
    if (s + 2 < nst) STG((char*)base);      // refill freed buffer for step s+2
  }

  const int r4 = (lane >> 4) * 4, cc = lane & 15;
  float* Cp = (MODE == 3) ? (C + (size_t)zt * ((size_t)TOK * N)) : C;
#pragma unroll
  for (int i = 0; i < MI; ++i) {
#pragma unroll
    for (int j = 0; j < NJ; ++j) {
      int col = bn + wc * (BN / 2) + j * 16 + cc;
      float bz = (MODE == 3) ? 0.0f : bias[col];
#pragma unroll
      for (int q = 0; q < 4; ++q) {
        int row = bm + wr * (BM / 2) + i * 16 + r4 + q;
        float v = (aH[i][j][q] + aM[i][j][q] * (1.0f / 2048.0f)) * (1.0f / 64.0f) + bz;
        if (MODE == 0 || MODE == 3) {
          Cp[(size_t)row * N + col] = v;
        } else {
          if (MODE == 1) v = fmaxf(v, 0.0f);
          f16 a, b; split16(v, a, b);
          Ch[(size_t)row * N + col] = a;
          Cl[(size_t)row * N + col] = b;
        }
      }
    }
  }
}

// ------- V^T tile builder: V section of qh/ql -> swizzled 64x64 tiles per (bh,kt) -------
__global__ __launch_bounds__(256)
void k_vt(const f16* __restrict__ qh, const f16* __restrict__ ql,
          f16* __restrict__ vtp) {
  __shared__ f16 T0[64][72];
  __shared__ f16 T1[64][72];
  const int bh = blockIdx.x, kt = blockIdx.y;
  const int b = bh / NH_, hd = bh % NH_;
  const int tid = threadIdx.x;
#pragma unroll
  for (int r = 0; r < 2; ++r) {
    int it = tid + 256 * r;
    int s = it >> 3, grp = it & 7;
    size_t g = ((size_t)(b * SEQ + kt * 64 + s)) * BQKV + 2 * H_ + hd * HD_ + grp * 8;
    *(f16x8*)&T0[s][grp * 8] = *(const f16x8*)&qh[g];
    *(f16x8*)&T1[s][grp * 8] = *(const f16x8*)&ql[g];
  }
  __syncthreads();
  f16* o0 = vtp + ((size_t)bh * 8 + kt) * 4096;
  f16* o1 = o0 + (size_t)96 * 8 * 4096;
#pragma unroll
  for (int r = 0; r < 2; ++r) {
    int it = tid + 256 * r;
    int d = it & 63, sg = it >> 6;
    f16x8 vh, vl;
#pragma unroll
    for (int u = 0; u < 8; ++u) { vh[u] = T0[sg * 8 + u][d]; vl[u] = T1[sg * 8 + u][d]; }
    *(f16x8*)&o0[swz(d, sg * 8)] = vh;
    *(f16x8*)&o1[swz(d, sg * 8)] = vl;
  }
}

// ---------- split-f16 MFMA flash attention (K register double-buffer prefetch) ----------
__global__ __launch_bounds__(256)
void k_flash_mfma(const f16* __restrict__ ph, const f16* __restrict__ pl,
                  const f16* __restrict__ vtp,
                  f16* __restrict__ oh, f16* __restrict__ ol) {
  __shared__ __align__(16) f16 VtH[2][4096];
  __shared__ __align__(16) f16 VtL[2][4096];
  __shared__ __align__(16) f16 PH[4096];
  __shared__ __align__(16) f16 PL[4096];
  __shared__ float PS[2][64];
  const int tid = threadIdx.x;
  const int lane = tid & 63, wid = tid >> 6;
  const int wr = wid >> 1, wc = wid & 1;
  const unsigned flat = blockIdx.x + 8u * blockIdx.y;
  const unsigned xcd = flat & 7u;
  const unsigned idx = flat >> 3;          // 0..95
  const int qt = idx & 7;
  const int bh = xcd * 12 + (idx >> 3);    // 0..95
  const int b = bh / NH_, hd = bh % NH_;
  const int rr = lane & 15, kg = (lane >> 4) * 8;
  const size_t tok0 = (size_t)b * SEQ;
  const char* vs0 = (const char*)(vtp + (size_t)bh * 8 * 4096);
  const char* vs1 = vs0 + (size_t)96 * 8 * 4096 * 2;

  auto STGV = [&](int kt, int buf) __attribute__((always_inline)) {
#pragma unroll
    for (int u = 0; u < 2; ++u) {
      int off = (wid + 4 * u) * 1024;
      GLDS16(vs0 + (size_t)kt * 8192 + off + lane * 16, (char*)&VtH[buf][0] + off);
      GLDS16(vs1 + (size_t)kt * 8192 + off + lane * 16, (char*)&VtL[buf][0] + off);
    }
  };

  auto KLOAD = [&](int kt, f16x8 (&kh)[2][2], f16x8 (&kl)[2][2]) __attribute__((always_inline)) {
#pragma unroll
    for (int jf = 0; jf < 2; ++jf)
#pragma unroll
      for (int ks = 0; ks < 2; ++ks) {
        size_t g = (tok0 + kt * 64 + wc * 32 + jf * 16 + rr) * (size_t)BQKV + H_ + hd * HD_ + ks * 32 + kg;
        kh[jf][ks] = *(const f16x8*)&ph[g];
        kl[jf][ks] = *(const f16x8*)&pl[g];
      }
  };

  f16x8 qfh[2][2], qfl[2][2];
#pragma unroll
  for (int ifr = 0; ifr < 2; ++ifr)
#pragma unroll
    for (int ks = 0; ks < 2; ++ks) {
      size_t g = (tok0 + qt * 64 + wr * 32 + ifr * 16 + rr) * (size_t)BQKV + hd * HD_ + ks * 32 + kg;
      qfh[ifr][ks] = *(const f16x8*)&ph[g];
      qfl[ifr][ks] = *(const f16x8*)&pl[g];
    }

  f32x4 oha[2][2], oma[2][2];
  float psum[2] = {0.f, 0.f};
#pragma unroll
  for (int i = 0; i < 2; ++i)
#pragma unroll
    for (int j = 0; j < 2; ++j)
#pragma unroll
      for (int q = 0; q < 4; ++q) { oha[i][j][q] = 0.0f; oma[i][j][q] = 0.0f; }

  auto BODY = [&](int kt, f16x8 (&kch)[2][2], f16x8 (&kcl)[2][2],
                  f16x8 (&knh)[2][2], f16x8 (&knl)[2][2]) __attribute__((always_inline)) {
    const int cb = kt & 1;
    // S^T = K.Q^T (3-pass): lane holds keys (lane>>4)*4+q for query rr
    f32x4 sh[2][2], sm2[2][2];   // [jf][ifr]
#pragma unroll
    for (int j = 0; j < 2; ++j)
#pragma unroll
      for (int i = 0; i < 2; ++i)
#pragma unroll
        for (int q = 0; q < 4; ++q) { sh[j][i][q] = 0.0f; sm2[j][i][q] = 0.0f; }
    __builtin_amdgcn_s_setprio(1);
#pragma unroll
    for (int jf = 0; jf < 2; ++jf)
#pragma unroll
      for (int ifr = 0; ifr < 2; ++ifr)
#pragma unroll
        for (int ks = 0; ks < 2; ++ks) {
          sh[jf][ifr]  = __builtin_amdgcn_mfma_f32_16x16x32_f16(kch[jf][ks], qfh[ifr][ks], sh[jf][ifr], 0, 0, 0);
          sm2[jf][ifr] = __builtin_amdgcn_mfma_f32_16x16x32_f16(kcl[jf][ks], qfh[ifr][ks], sm2[jf][ifr], 0, 0, 0);
          sm2[jf][ifr] = __builtin_amdgcn_mfma_f32_16x16x32_f16(kch[jf][ks], qfl[ifr][ks], sm2[jf][ifr], 0, 0, 0);
        }
    __builtin_amdgcn_s_setprio(0);
    // softmax numerator into registers
    f16x4 pv4h[2][2], pv4l[2][2];
#pragma unroll
    for (int ifr = 0; ifr < 2; ++ifr)
#pragma unroll
      for (int jf = 0; jf < 2; ++jf)
#pragma unroll
        for (int q = 0; q < 4; ++q) {
          float sval = (sh[jf][ifr][q] + sm2[jf][ifr][q] * (1.0f / 2048.0f)) * 0.125f;
          float p = expf(sval);
          psum[ifr] += p;
          f16 a, b2; split16(p, a, b2);
          pv4h[ifr][jf][q] = a; pv4l[ifr][jf][q] = b2;
        }
    // barrier #1: all waves done reading PH/PL and Vt[cb^1] from prev iter
    __builtin_amdgcn_s_barrier();
    __builtin_amdgcn_sched_barrier(0);
    if (kt + 1 < SEQ / 64) STGV(kt + 1, cb ^ 1);
    // P hi/lo -> LDS (ds_write_b64, 4 consecutive keys per store)
#pragma unroll
    for (int ifr = 0; ifr < 2; ++ifr)
#pragma unroll
      for (int jf = 0; jf < 2; ++jf) {
        int qi = wr * 32 + ifr * 16 + rr;
        int j0 = wc * 32 + jf * 16 + (lane >> 4) * 4;
        *(f16x4*)&PH[swz(qi, j0)] = pv4h[ifr][jf];
        *(f16x4*)&PL[swz(qi, j0)] = pv4l[ifr][jf];
      }
    // barrier #2: P visible; V(kt) landed (only STGV(kt+1)'s 4 may remain in flight)
    if (kt + 1 < SEQ / 64) {
      asm volatile("s_waitcnt vmcnt(4) lgkmcnt(0)" ::: "memory");
    } else {
      asm volatile("s_waitcnt vmcnt(0) lgkmcnt(0)" ::: "memory");
    }
    __builtin_amdgcn_s_barrier();
    __builtin_amdgcn_sched_barrier(0);
    // K(kt+1) register prefetch: lands under the PV phase below (T14)
    if (kt + 1 < SEQ / 64) KLOAD(kt + 1, knh, knl);
    // PV (3-pass): A = P from LDS, B = V^T from staged LDS tile
#pragma unroll
    for (int ks = 0; ks < 2; ++ks) {
      f16x8 pfh[2], pfl[2], vfh[2], vfl[2];
#pragma unroll
      for (int ifr = 0; ifr < 2; ++ifr) {
        pfh[ifr] = *(const f16x8*)&PH[swz(wr * 32 + ifr * 16 + rr, ks * 32 + kg)];
        pfl[ifr] = *(const f16x8*)&PL[swz(wr * 32 + ifr * 16 + rr, ks * 32 + kg)];
      }
#pragma unroll
      for (int jf = 0; jf < 2; ++jf) {
        vfh[jf] = *(const f16x8*)&VtH[cb][swz(wc * 32 + jf * 16 + rr, ks * 32 + kg)];
        vfl[jf] = *(const f16x8*)&VtL[cb][swz(wc * 32 + jf * 16 + rr, ks * 32 + kg)];
      }
      __builtin_amdgcn_s_setprio(1);
#pragma unroll
      for (int ifr = 0; ifr < 2; ++ifr)
#pragma unroll
        for (int jf = 0; jf < 2; ++jf) {
          oha[ifr][jf] = __builtin_amdgcn_mfma_f32_16x16x32_f16(pfh[ifr], vfh[jf], oha[ifr][jf], 0, 0, 0);
          oma[ifr][jf] = __builtin_amdgcn_mfma_f32_16x16x32_f16(pfh[ifr], vfl[jf], oma[ifr][jf], 0, 0, 0);
          oma[ifr][jf] = __builtin_amdgcn_mfma_f32_16x16x32_f16(pfl[ifr], vfh[jf], oma[ifr][jf], 0, 0, 0);
        }
      __builtin_amdgcn_s_setprio(0);
    }
  };

  f16x8 kAh[2][2], kAl[2][2], kBh[2][2], kBl[2][2];
  KLOAD(0, kAh, kAl);
  STGV(0, 0);
  for (int kt = 0; kt < SEQ / 64; kt += 2) {
    BODY(kt,     kAh, kAl, kBh, kBl);
    BODY(kt + 1, kBh, kBl, kAh, kAl);
  }

  // denominator: reduce over key lane-groups, then across wc via LDS
#pragma unroll
  for (int ifr = 0; ifr < 2; ++ifr) {
    psum[ifr] += __shfl_xor(psum[ifr], 16);
    psum[ifr] += __shfl_xor(psum[ifr], 32);
  }
  if (lane < 16) {
    PS[wc][wr * 32 + lane]      = psum[0];
    PS[wc][wr * 32 + 16 + lane] = psum[1];
  }
  __syncthreads();

#pragma unroll
  for (int ifr = 0; ifr < 2; ++ifr)
#pragma unroll
    for (int jf = 0; jf < 2; ++jf)
#pragma unroll
      for (int q = 0; q < 4; ++q) {
        int i = wr * 32 + ifr * 16 + (lane >> 4) * 4 + q;
        float inv = 1.0f / (PS[0][i] + PS[1][i]);
        float o = (oha[ifr][jf][q] + oma[ifr][jf][q] * (1.0f / 2048.0f)) * inv;
        size_t g = (tok0 + qt * 64 + i) * (size_t)H_ + hd * HD_ + wc * 32 + jf * 16 + rr;
        f16 a, b2; split16(o, a, b2);
        oh[g] = a; ol[g] = b2;
      }
}

// ---------------- x = LN(xin + (p0+p1) + bias)*g + b, + f16 planes ----------------
__global__ __launch_bounds__(256)
void k_ln_res3(const float* __restrict__ xin, const float* __restrict__ part,
               const float* __restrict__ bcol,
               const float* __restrict__ g, const float* __restrict__ bb,
               float* __restrict__ xout, f16* __restrict__ xh, f16* __restrict__ xl) {
  __shared__ float red[8];
  int t = blockIdx.x;
  const float* xr = xin + (size_t)t * H_;
  const float* p0 = part + (size_t)t * H_;
  const float* p1 = part + (size_t)TOK * H_ + (size_t)t * H_;
  float v[3];
#pragma unroll
  for (int j = 0; j < 3; ++j) {
    int hh = threadIdx.x + 256 * j;
    v[j] = xr[hh] + ((p0[hh] + p1[hh]) + bcol[hh]);
  }
  float s = v[0] + v[1] + v[2];
  s = wave_sum(s);
  int w = threadIdx.x >> 6;
  if ((threadIdx.x & 63) == 0) red[w] = s;
  __syncthreads();
  float mu = (red[0] + red[1] + red[2] + red[3]) * (1.0f / 768.0f);
  float q = 0.f;
#pragma unroll
  for (int j = 0; j < 3; ++j) { float d = v[j] - mu; q = fmaf(d, d, q); }
  q = wave_sum(q);
  if ((threadIdx.x & 63) == 0) red[4 + w] = q;
  __syncthreads();
  float var = (red[4] + red[5] + red[6] + red[7]) * (1.0f / 768.0f);
  float rinv = 1.0f / sqrtf(var + 1e-5f);
#pragma unroll
  for (int j = 0; j < 3; ++j) {
    int hh = threadIdx.x + 256 * j;
    float val = fmaf(g[hh], (v[j] - mu) * rinv, bb[hh]);
    size_t idx = (size_t)t * H_ + hh;
    xout[idx] = val;
    f16 a, b; split16(val, a, b);
    xh[idx] = a; xl[idx] = b;
  }
}

// ------- LM: reduce 4 split-K partials + bias -> out0, argmax, histogram -------
__global__ __launch_bounds__(64)
void k_argmax2(const float* __restrict__ part, const float* __restrict__ blm,
               float* __restrict__ out0, int* __restrict__ ix,
               int* __restrict__ counts) {
  int t = blockIdx.x, l = threadIdx.x;
  const size_t S = (size_t)TOK * V_;
  size_t c0 = (size_t)t * V_ + l;
  size_t c1 = c0 + 64;
  float v0 = ((part[c0] + part[S + c0]) + part[2 * S + c0]) + part[3 * S + c0] + blm[l];
  float v1 = ((part[c1] + part[S + c1]) + part[2 * S + c1]) + part[3 * S + c1] + blm[l + 64];
  out0[c0] = v0;
  out0[c1] = v1;
  float best = v0; int bi = l;
  if (v1 > best) { best = v1; bi = 64 + l; }
#pragma unroll
  for (int m = 1; m < 64; m <<= 1) {
    float ov = __shfl_xor(best, m);
    int oi = __shfl_xor(bi, m);
    if (ov > best || (ov == best && oi < bi)) { best = ov; bi = oi; }
  }
  if (l == 0) { ix[t] = bi; atomicAdd(&counts[bi], 1); }
}

// ---------------- route bucketing: scan + chunk table ----------------
__global__ __launch_bounds__(128)
void k_prep(const int* __restrict__ counts, int* __restrict__ offsets,
            int* __restrict__ cursors, int4* __restrict__ chunks,
            int* __restrict__ nchunks) {
  __shared__ int s[128];
  int r = threadIdx.x;
  int c = counts[r];
  s[r] = c; __syncthreads();
  for (int d = 1; d < 128; d <<= 1) {
    int v = (r >= d) ? s[r - d] : 0; __syncthreads();
    s[r] += v; __syncthreads();
  }
  int off = s[r] - c;
  offsets[r] = off;
  cursors[r] = 0;
  int nch = (c + 15) >> 4;
  __syncthreads();
  s[r] = nch; __syncthreads();
  for (int d = 1; d < 128; d <<= 1) {
    int v = (r >= d) ? s[r - d] : 0; __syncthreads();
    s[r] += v; __syncthreads();
  }
  int cb = s[r] - nch;
  for (int u = 0; u < nch; ++u) {
    int rem = c - u * 16;
    chunks[cb + u] = make_int4(r, off + u * 16, rem < 16 ? rem : 16, 0);
  }
  if (r == 127) *nchunks = s[127];
}

__global__ __launch_bounds__(256)
void k_scatter(const int* __restrict__ ix, const int* __restrict__ offsets,
               int* __restrict__ cursors, int* __restrict__ bucket) {
  int t = blockIdx.x * 256 + threadIdx.x;
  int r = ix[t];
  int p = atomicAdd(&cursors[r], 1);
  bucket[offsets[r] + p] = t;
}

// ------- transpose-convert routed W: [r][h][v] fp32 -> [r][v][h] f16 hi/lo -------
__global__ __launch_bounds__(256)
void k_convT(const float* __restrict__ W, f16* __restrict__ wth, f16* __restrict__ wtl) {
  __shared__ float tile[64][65];
  const int r = blockIdx.x, vb = blockIdx.y * 64;
  const int tid = threadIdx.x;
  const int la = tid & 63, wv = tid >> 6;
  for (int ht = 0; ht < H_ / 64; ++ht) {
    int h0 = ht * 64;
#pragma unroll
    for (int i = 0; i < 16; ++i) {
      int row = wv + i * 4;
      tile[row][la] = W[(size_t)r * (H_ * V_) + (size_t)(h0 + row) * V_ + vb + la];
    }
    __syncthreads();
#pragma unroll
    for (int i = 0; i < 16; ++i) {
      int vl = wv + i * 4;
      float w = tile[la][vl];
      f16 a, b; split16(w, a, b);
      size_t o = ((size_t)r * V_ + vb + vl) * H_ + h0 + la;
      wth[o] = a; wtl[o] = b;
    }
    __syncthreads();
  }
}

// ------- MFMA routed head: one chunk (<=16 tokens, 1 route) per block -------
__global__ __launch_bounds__(256)
void k_sublevel3(const f16* __restrict__ xh, const f16* __restrict__ xl,
                 const f16* __restrict__ wth, const f16* __restrict__ wtl,
                 const float* __restrict__ bias, const int* __restrict__ bucket,
                 const int4* __restrict__ chunks, const int* __restrict__ nchunks,
                 float* __restrict__ out) {
  int c = blockIdx.x;
  if (c >= *nchunks) return;
  int4 ch = chunks[c];
  int r = ch.x, ts = ch.y, nt = ch.z;
  __shared__ int toks[16];
  int tid = threadIdx.x;
  if (tid < 16) toks[tid] = bucket[ts + (tid < nt ? tid : 0)];
  __syncthreads();
  const int lane = tid & 63, wid = tid >> 6;
  const int rr = lane & 15, kg = (lane >> 4) * 8;
  const int myTok = toks[rr];
  const size_t abase = (size_t)myTok * H_ + kg;

  f32x4 aH[2], aM[2];
#pragma unroll
  for (int j = 0; j < 2; ++j)
#pragma unroll
    for (int q = 0; q < 4; ++q) { aH[j][q] = 0.0f; aM[j][q] = 0.0f; }

  size_t wb[2];
#pragma unroll
  for (int j = 0; j < 2; ++j)
    wb[j] = ((size_t)r * V_ + wid * 32 + j * 16 + rr) * H_ + kg;

  for (int k0 = 0; k0 < H_; k0 += 32) {
    f16x8 ah = *(const f16x8*)&xh[abase + k0];
    f16x8 al = *(const f16x8*)&xl[abase + k0];
#pragma unroll
    for (int j = 0; j < 2; ++j) {
      f16x8 bh = *(const f16x8*)&wth[wb[j] + k0];
      f16x8 bl = *(const f16x8*)&wtl[wb[j] + k0];
      aH[j] = __builtin_amdgcn_mfma_f32_16x16x32_f16(ah, bh, aH[j], 0, 0, 0);
      aM[j] = __builtin_amdgcn_mfma_f32_16x16x32_f16(ah, bl, aM[j], 0, 0, 0);
      aM[j] = __builtin_amdgcn_mfma_f32_16x16x32_f16(al, bh, aM[j], 0, 0, 0);
    }
  }

  const int r4 = (lane >> 4) * 4, cc = lane & 15;
#pragma unroll
  for (int j = 0; j < 2; ++j) {
#pragma unroll
    for (int q = 0; q < 4; ++q) {
      int row = r4 + q;
      if (row < nt) {
        int col = wid * 32 + j * 16 + cc;
        out[(size_t)toks[row] * V_ + col] =
            aH[j][q] + aM[j][q] * (1.0f / 2048.0f) + bias[(size_t)r * V_ + col];
      }
    }
  }
}

extern "C" void kernel_launch(void* const* d_in, const int* in_sizes, int n_in,
                              void* d_out, int out_size, void* d_ws, size_t ws_size,
                              hipStream_t stream) {
  const int*   lid  = (const int*)d_in[0];
  const int*   sid  = (const int*)d_in[1];
  const float* be   = (const float*)d_in[2];
  const float* se   = (const float*)d_in[3];
  const float* Wqkv = (const float*)d_in[4];
  const float* bqkv = (const float*)d_in[5];
  const float* Wo   = (const float*)d_in[6];
  const float* bo   = (const float*)d_in[7];
  const float* g1   = (const float*)d_in[8];
  const float* b1n  = (const float*)d_in[9];
  const float* W1   = (const float*)d_in[10];
  const float* b1f  = (const float*)d_in[11];
  const float* W2   = (const float*)d_in[12];
  const float* b2f  = (const float*)d_in[13];
  const float* g2   = (const float*)d_in[14];
  const float* b2n  = (const float*)d_in[15];
  const float* Wlm  = (const float*)d_in[16];
  const float* blm  = (const float*)d_in[17];
  const float* Wrt  = (const float*)d_in[18];
  const float* brt  = (const float*)d_in[19];

  char* ws = (char*)d_ws;
  float* x    = (float*)(ws + 0);              // 12,582,912
  f16*   xh   = (f16*)  (ws + 12582912);       //  6,291,456
  f16*   xl   = (f16*)  (ws + 18874368);       //  6,291,456
  f16*   qh   = (f16*)  (ws + 25165824);       // 18,874,368 (midh aliases)
  f16*   ql   = (f16*)  (ws + 44040192);       // 18,874,368 (midl aliases)
  f16*   midh = qh;
  f16*   midl = ql;
  f16*   ath  = (f16*)  (ws + 62914560);       //  6,291,456
  f16*   atl  = (f16*)  (ws + 69206016);       //  6,291,456
  float* bufY = (float*)(ws + 75497472);       // 12,582,912
  // vtp: swizzled V^T tiles (2 planes x 96 x 8 x 4096 f16 = 12.58 MB), aliases bufY;
  // live QKV->flash only (dead before FFN2's pF and before pLM).
  f16*   vtp  = (f16*)  (ws + 75497472);
  // split-K partial regions (aliases of dead buffers at their point of use):
  float* pO   = (float*)(ws + 25165824);       // O-proj partials: 2 x 12.58 MB (qh/ql dead)
  float* pF   = (float*)(ws + 62914560);       // FFN2 partials: 2 x 12.58 MB (ath/atl+bufY dead)
  float* pLM  = bufY;                          // LM partials: 4 x 2.10 MB
  // routed-W transposed planes (qh..atl region, dead after last FFN2/LN2):
  f16*   wth  = (f16*)  (ws + 25165824);       // 25,165,824
  f16*   wtl  = (f16*)  (ws + 50331648);       // 25,165,824 (ends at bufY)
  f16*   wsh  = (f16*)  (ws + 88080384);       //  3,538,944
  f16*   wsl  = (f16*)  (ws + 91619328);       //  3,538,944
  f16*   wlmh = (f16*)  (ws + 95158272);
  f16*   wlml = (f16*)  (ws + 95354880);
  int*   ix   = (int*)  (ws + 95551488);       // 16,384
  int*   counts  = (int*)(ws + 95567872);      // 512
  int*   cursors = (int*)(ws + 95568384);      // 512
  int*   offsets = (int*)(ws + 95568896);      // 1,024
  int4*  chunks  = (int4*)(ws + 95569920);     // 6,144
  int*   nchunks = (int*)(ws + 95576064);      // 256
  int*   bucket  = (int*)(ws + 95576320);      // 16,384
  const size_t need = 95592704;
  if (ws_size < need) return;

  bool big = ws_size >= 95600640ull + 265000000ull;
  f16 *bWqh = nullptr, *bWql = nullptr, *bWoh = nullptr, *bWol = nullptr,
      *bW1h = nullptr, *bW1l = nullptr, *bW2h = nullptr, *bW2l = nullptr;
  if (big) {
    char* p = ws + 95600640;
    bWqh = (f16*)p; p += 42467328;
    bWql = (f16*)p; p += 42467328;
    bWoh = (f16*)p; p += 14155776;
    bWol = (f16*)p; p += 14155776;
    bW1h = (f16*)p; p += 37748736;
    bW1l = (f16*)p; p += 37748736;
    bW2h = (f16*)p; p += 37748736;
    bW2l = (f16*)p; p += 37748736;
    k_convert<<<2048, 256, 0, stream>>>(Wqkv, bWqh, bWql, L_ * BQKV * H_ / 4, 64.f);
    k_convert<<<2048, 256, 0, stream>>>(Wo,   bWoh, bWol, L_ * H_ * H_ / 4, 64.f);
    k_convert<<<2048, 256, 0, stream>>>(W1,   bW1h, bW1l, L_ * F_ * H_ / 4, 64.f);
    k_convert<<<2048, 256, 0, stream>>>(W2,   bW2h, bW2l, L_ * H_ * F_ / 4, 64.f);
  }
  k_convert<<<96, 256, 0, stream>>>(Wlm, wlmh, wlml, V_ * H_ / 4, 64.f);

  float* out0 = (float*)d_out;
  float* out1 = out0 + (size_t)TOK * V_;

  k_embed2<<<TOK, 256, 0, stream>>>(lid, sid, be, se, x, xh, xl, counts);

  for (int l = 0; l < L_; ++l) {
    const float* bqkv_l = bqkv + (size_t)l * BQKV;
    const float* bo_l   = bo   + (size_t)l * H_;
    const float* g1_l   = g1   + (size_t)l * H_;
    const float* b1n_l  = b1n  + (size_t)l * H_;
    const float* b1f_l  = b1f  + (size_t)l * F_;
    const float* b2f_l  = b2f  + (size_t)l * H_;
    const float* g2_l   = g2   + (size_t)l * H_;
    const float* b2n_l  = b2n  + (size_t)l * H_;

    const f16 *wh, *wl2;
    // ---- QKV: planes out (128x128) ----
    if (big) { wh = bWqh + (size_t)l * BQKV * H_; wl2 = bWql + (size_t)l * BQKV * H_; }
    else {
      k_convert<<<1728, 256, 0, stream>>>(Wqkv + (size_t)l * BQKV * H_, wsh, wsl, BQKV * H_ / 4, 64.f);
      wh = wsh; wl2 = wsl;
    }
    k_gemm5<128, 128, 2, 1><<<dim3(TOK / 128, BQKV / 128, 1), 256, 0, stream>>>(
        xh, xl, wh, wl2, bqkv_l, nullptr, qh, ql, BQKV, H_);
    k_vt<<<dim3(96, 8), 256, 0, stream>>>(qh, ql, vtp);
    k_flash_mfma<<<dim3(SEQ / 64, BATCH * NH_), 256, 0, stream>>>(qh, ql, vtp, ath, atl);
    // ---- O-proj: split-K2 partials (qh/ql region now dead) ----
    if (big) { wh = bWoh + (size_t)l * H_ * H_; wl2 = bWol + (size_t)l * H_ * H_; }
    else {
      k_convert<<<576, 256, 0, stream>>>(Wo + (size_t)l * H_ * H_, wsh, wsl, H_ * H_ / 4, 64.f);
      wh = wsh; wl2 = wsl;
    }
    k_gemm5<128, 128, 3, 2><<<dim3(TOK / 128, H_ / 128, 2), 256, 0, stream>>>(
        ath, atl, wh, wl2, nullptr, pO, nullptr, nullptr, H_, H_);
    k_ln_res3<<<TOK, 256, 0, stream>>>(x, pO, bo_l, g1_l, b1n_l, x, xh, xl);
    // ---- FFN1 (relu, planes out into mid = qh/ql region) ----
    if (big) { wh = bW1h + (size_t)l * F_ * H_; wl2 = bW1l + (size_t)l * F_ * H_; }
    else {
      k_convert<<<1536, 256, 0, stream>>>(W1 + (size_t)l * F_ * H_, wsh, wsl, F_ * H_ / 4, 64.f);
      wh = wsh; wl2 = wsl;
    }
    k_gemm5<128, 128, 1, 1><<<dim3(TOK / 128, F_ / 128, 1), 256, 0, stream>>>(
        xh, xl, wh, wl2, b1f_l, nullptr, midh, midl, F_, H_);
    // ---- FFN2: split-K2 partials (ath/atl + bufY dead) ----
    if (big) { wh = bW2h + (size_t)l * H_ * F_; wl2 = bW2l + (size_t)l * H_ * F_; }
    else {
      k_convert<<<1536, 256, 0, stream>>>(W2 + (size_t)l * H_ * F_, wsh, wsl, H_ * F_ / 4, 64.f);
      wh = wsh; wl2 = wsl;
    }
    k_gemm5<128, 128, 3, 2><<<dim3(TOK / 128, H_ / 128, 2), 256, 0, stream>>>(
        midh, midl, wh, wl2, nullptr, pF, nullptr, nullptr, H_, F_);
    k_ln_res3<<<TOK, 256, 0, stream>>>(x, pF, b2f_l, g2_l, b2n_l, x, xh, xl);
  }

  // ---- LM head: split-K4 partials into bufY ----
  k_gemm5<64, 64, 3, 4><<<dim3(TOK / 64, V_ / 64, 4), 256, 0, stream>>>(
      xh, xl, wlmh, wlml, nullptr, pLM, nullptr, nullptr, V_, H_);
  // ---- routed-W transpose planes (qh..atl region dead now) ----
  k_convT<<<dim3(V_, 2), 256, 0, stream>>>(Wrt, wth, wtl);
  k_argmax2<<<TOK, 64, 0, stream>>>(pLM, blm, out0, ix, counts);
  k_prep<<<1, 128, 0, stream>>>(counts, offsets, cursors, chunks, nchunks);
  k_scatter<<<TOK / 256, 256, 0, stream>>>(ix, offsets, cursors, bucket);
  k_sublevel3<<<384, 256, 0, stream>>>(xh, xl, wth, wtl, brt, bucket, chunks, nchunks, out1);
}

// Round 16
// 3217.447 us; speedup vs baseline: 1.0580x; 1.0580x over previous
//
#include <hip/hip_runtime.h>
#include <cstdint>
#include <cstddef>

#define TOK 4096      // B*S
#define HD_ 64
#define NH_ 12
#define H_ 768
#define F_ 2048
#define V_ 128
#define L_ 12
#define SEQ 512
#define BQKV (3*H_)
#define BATCH 8

typedef _Float16 f16;
typedef _Float16 f16x8 __attribute__((ext_vector_type(8)));
typedef _Float16 f16x4 __attribute__((ext_vector_type(4)));
typedef float    f32x4 __attribute__((ext_vector_type(4)));

#define GLDS16(g, l) __builtin_amdgcn_global_load_lds( \
    (const __attribute__((address_space(1))) uint32_t*)(g), \
    (__attribute__((address_space(3))) uint32_t*)(l), 16, 0, 0)

__device__ __forceinline__ float wave_sum(float v) {
#pragma unroll
  for (int m = 32; m >= 1; m >>= 1) v += __shfl_xor(v, m);
  return v;
}

__device__ __forceinline__ void split16(float v, f16& h, f16& lo) {
  h = (f16)v;
  lo = (f16)((v - (float)h) * 2048.0f);
}

// XOR-swizzled element index into a [64][64] f16 tile (128B rows)
__device__ __forceinline__ int swz(int r, int c) {
  int byte = (r << 7) + (c << 1);
  byte ^= (r & 7) << 4;
  return byte >> 1;
}

// ---------------- fp32 -> (hi, lo*2^11) f16 planes, optional pre-scale ----------------
__global__ __launch_bounds__(256)
void k_convert(const float* __restrict__ src, f16* __restrict__ h, f16* __restrict__ l,
               int n4, float scale) {
  int i = blockIdx.x * 256 + threadIdx.x;
  int stride = gridDim.x * 256;
  for (; i < n4; i += stride) {
    float4 v = ((const float4*)src)[i];
    v.x *= scale; v.y *= scale; v.z *= scale; v.w *= scale;
    f16x4 vh, vl;
    f16 a, b;
    split16(v.x, a, b); vh[0] = a; vl[0] = b;
    split16(v.y, a, b); vh[1] = a; vl[1] = b;
    split16(v.z, a, b); vh[2] = a; vl[2] = b;
    split16(v.w, a, b); vh[3] = a; vl[3] = b;
    ((f16x4*)h)[i] = vh;
    ((f16x4*)l)[i] = vl;
  }
}

// ---------------- embedding + planes (+ zero route counters) ----------------
__global__ __launch_bounds__(256)
void k_embed2(const int* __restrict__ lid, const int* __restrict__ sid,
              const float* __restrict__ be, const float* __restrict__ se,
              float* __restrict__ x, f16* __restrict__ xh, f16* __restrict__ xl,
              int* __restrict__ counts) {
  int t = blockIdx.x;
  if (t == 0 && threadIdx.x < V_) counts[threadIdx.x] = 0;
  int li = lid[t], si = sid[t];
  const float* bp = be + (size_t)li * H_;
  const float* sp = se + (size_t)si * H_;
  size_t base = (size_t)t * H_;
#pragma unroll
  for (int j = 0; j < 3; ++j) {
    int hh = threadIdx.x + 256 * j;
    float v = bp[hh] + sp[hh];
    x[base + hh] = v;
    f16 a, b; split16(v, a, b);
    xh[base + hh] = a; xl[base + hh] = b;
  }
}

// ---------- split-f16 MFMA GEMM: regs-staged frags + pure-reg MFMA cluster ----------
// C[M,N] = A[M,K] @ B[N,K]^T. B planes pre-scaled x64.
// acc_hi = Ah.Bh ; acc_mid = Ah.Bl + Al.Bh ; result = (hi + mid/2048)/64.
// MODE 0: fp32 out + bias; 1: relu+planes; 2: planes; 3: fp32 partial (split-K, no bias)
template<int BM, int BN, int MODE, int SPLIT>
__global__ __launch_bounds__(256, 2)
void k_gemm5(const f16* __restrict__ Ah, const f16* __restrict__ Al,
             const f16* __restrict__ Bh, const f16* __restrict__ Bl,
             const float* __restrict__ bias, float* __restrict__ C,
             f16* __restrict__ Ch, f16* __restrict__ Cl,
             int N, int K) {
  constexpr int MI = BM / 32, NJ = BN / 32;
  constexpr int IA = BM / 64, IB = BN / 64;
  constexpr int ABYT = BM * 64, BBYT = BN * 64;
  constexpr int BUFB = 2 * ABYT + 2 * BBYT;
  constexpr int NGL = 2 * (IA + IB);
  __shared__ __align__(16) char sm_[2 * BUFB];
  const int tid = threadIdx.x;
  const int lane = tid & 63, wid = tid >> 6;
  const int wr = wid >> 1, wc = wid & 1;

  // XCD-locality remap (gridDim.x % 8 == 0; pure index permutation)
  const unsigned flat = blockIdx.x + gridDim.x * (blockIdx.y + gridDim.y * blockIdx.z);
  const unsigned G = gridDim.x >> 3;
  const unsigned xcd = flat & 7u;
  const unsigned idx = flat >> 3;
  const unsigned mt = xcd * G + idx % G;
  const unsigned rest = idx / G;
  const unsigned nt = rest % gridDim.y;
  const unsigned zt = rest / gridDim.y;

  const int bm = mt * BM, bn = nt * BN;
  const size_t rs = (size_t)K * 2;
  const size_t koff = (size_t)zt * (size_t)(K / SPLIT) * 2;

  const int srow = tid >> 2, schk = tid & 3;
  const char* ga[2][IA];
  const char* gb[2][IB];
#pragma unroll
  for (int u = 0; u < IA; ++u) {
    int row = u * 64 + srow;
    int c = schk ^ ((row >> 1) & 3);
    ga[0][u] = (const char*)Ah + (size_t)(bm + row) * rs + c * 16 + koff;
    ga[1][u] = (const char*)Al + (size_t)(bm + row) * rs + c * 16 + koff;
  }
#pragma unroll
  for (int u = 0; u < IB; ++u) {
    int row = u * 64 + srow;
    int c = schk ^ ((row >> 1) & 3);
    gb[0][u] = (const char*)Bh + (size_t)(bn + row) * rs + c * 16 + koff;
    gb[1][u] = (const char*)Bl + (size_t)(bn + row) * rs + c * 16 + koff;
  }

  const int rr = lane & 15, cgrp = lane >> 4;
  int aoff[MI][2], boff[NJ][2];
#pragma unroll
  for (int i = 0; i < MI; ++i) {
    int row = wr * (BM / 2) + i * 16 + rr;
    int sw = (cgrp ^ ((row >> 1) & 3)) * 16;
    aoff[i][0] = row * 64 + sw;
    aoff[i][1] = ABYT + row * 64 + sw;
  }
#pragma unroll
  for (int j = 0; j < NJ; ++j) {
    int row = wc * (BN / 2) + j * 16 + rr;
    int sw = (cgrp ^ ((row >> 1) & 3)) * 16;
    boff[j][0] = 2 * ABYT + row * 64 + sw;
    boff[j][1] = 2 * ABYT + BBYT + row * 64 + sw;
  }

  f32x4 aH[MI][NJ], aM[MI][NJ];
#pragma unroll
  for (int i = 0; i < MI; ++i)
#pragma unroll
    for (int j = 0; j < NJ; ++j)
#pragma unroll
      for (int q = 0; q < 4; ++q) { aH[i][j][q] = 0.0f; aM[i][j][q] = 0.0f; }

  auto STG = [&](char* bufbase) __attribute__((always_inline)) {
    char* base = bufbase + wid * 1024;
#pragma unroll
    for (int u = 0; u < IA; ++u) {
      GLDS16(ga[0][u], base + u * 4096);
      GLDS16(ga[1][u], base + ABYT + u * 4096);
      ga[0][u] += 64; ga[1][u] += 64;
    }
#pragma unroll
    for (int u = 0; u < IB; ++u) {
      GLDS16(gb[0][u], base + 2 * ABYT + u * 4096);
      GLDS16(gb[1][u], base + 2 * ABYT + BBYT + u * 4096);
      gb[0][u] += 64; gb[1][u] += 64;
    }
  };

  char* b0 = sm_;
  char* b1 = sm_ + BUFB;
  const int nst = (K / SPLIT) / 32;   // >= 2 for all shapes used
  STG(b0);
  STG(b1);
  for (int s = 0; s < nst; ++s) {
    if (s < nst - 1) {
      asm volatile("s_waitcnt vmcnt(%0)" :: "i"(NGL) : "memory");
    } else {
      asm volatile("s_waitcnt vmcnt(0)" ::: "memory");
    }
    __builtin_amdgcn_s_barrier();
    __builtin_amdgcn_sched_barrier(0);
    const char* base = (s & 1) ? b1 : b0;
    f16x8 fb[NJ][2], fa[MI][2];
#pragma unroll
    for (int j = 0; j < NJ; ++j) {
      fb[j][0] = *(const f16x8*)(base + boff[j][0]);
      fb[j][1] = *(const f16x8*)(base + boff[j][1]);
    }
#pragma unroll
    for (int i = 0; i < MI; ++i) {
      fa[i][0] = *(const f16x8*)(base + aoff[i][0]);
      fa[i][1] = *(const f16x8*)(base + aoff[i][1]);
    }
    asm volatile("s_waitcnt lgkmcnt(0)" ::: "memory");
    __builtin_amdgcn_s_barrier();           // all waves' frags in regs: buffer free
    __builtin_amdgcn_sched_barrier(0);
    if (s + 2 < nst) STG((char*)base);      // refill freed buffer for step s+2
    __builtin_amdgcn_s_setprio(1);
#pragma unroll
    for (int i = 0; i < MI; ++i) {
#pragma unroll
      for (int j = 0; j < NJ; ++j) {
        aH[i][j] = __builtin_amdgcn_mfma_f32_16x16x32_f16(fa[i][0], fb[j][0], aH[i][j], 0, 0, 0);
        aM[i][j] = __builtin_amdgcn_mfma_f32_16x16x32_f16(fa[i][0], fb[j][1], aM[i][j], 0, 0, 0);
        aM[i][j] = __builtin_amdgcn_mfma_f32_16x16x32_f16(fa[i][1], fb[j][0], aM[i][j], 0, 0, 0);
      }
    }
    __builtin_amdgcn_s_setprio(0);
  }

  const int r4 = (lane >> 4) * 4, cc = lane & 15;
  float* Cp = (MODE == 3) ? (C + (size_t)zt * ((size_t)TOK * N)) : C;
#pragma unroll
  for (int i = 0; i < MI; ++i) {
#pragma unroll
    for (int j = 0; j < NJ; ++j) {
      int col = bn + wc * (BN / 2) + j * 16 + cc;
      float bz = (MODE == 3) ? 0.0f : bias[col];
#pragma unroll
      for (int q = 0; q < 4; ++q) {
        int row = bm + wr * (BM / 2) + i * 16 + r4 + q;
        float v = (aH[i][j][q] + aM[i][j][q] * (1.0f / 2048.0f)) * (1.0f / 64.0f) + bz;
        if (MODE == 0 || MODE == 3) {
          Cp[(size_t)row * N + col] = v;
        } else {
          if (MODE == 1) v = fmaxf(v, 0.0f);
          f16 a, b; split16(v, a, b);
          Ch[(size_t)row * N + col] = a;
          Cl[(size_t)row * N + col] = b;
        }
      }
    }
  }
}

// ---------- split-f16 MFMA flash attention ----------
// V staged to LDS (transposed+swizzled); QK^T swapped (S^T = mfma(K,Q),
// bit-identical S values) so P packs to LDS with ds_write_b64 (8 vector writes
// instead of 32 scalar). PV reads P and V^T frags from LDS.
__global__ __launch_bounds__(256)
void k_flash_mfma(const f16* __restrict__ ph, const f16* __restrict__ pl,
                  f16* __restrict__ oh, f16* __restrict__ ol) {
  __shared__ __align__(16) f16 VtH[4096];
  __shared__ __align__(16) f16 VtL[4096];
  __shared__ __align__(16) f16 PH[4096];
  __shared__ __align__(16) f16 PL[4096];
  __shared__ float PS[2][64];
  const int tid = threadIdx.x;
  const int lane = tid & 63, wid = tid >> 6;
  const int wr = wid >> 1, wc = wid & 1;
  const unsigned flat = blockIdx.x + 8u * blockIdx.y;
  const unsigned xcd = flat & 7u;
  const unsigned idx = flat >> 3;          // 0..95
  const int qt = idx & 7;
  const int bh = xcd * 12 + (idx >> 3);    // 0..95
  const int b = bh / NH_, hd = bh % NH_;
  const int rr = lane & 15, kg = (lane >> 4) * 8;
  const size_t tok0 = (size_t)b * SEQ;

  f16x8 qfh[2][2], qfl[2][2];
#pragma unroll
  for (int ifr = 0; ifr < 2; ++ifr)
#pragma unroll
    for (int ks = 0; ks < 2; ++ks) {
      size_t g = (tok0 + qt * 64 + wr * 32 + ifr * 16 + rr) * (size_t)BQKV + hd * HD_ + ks * 32 + kg;
      qfh[ifr][ks] = *(const f16x8*)&ph[g];
      qfl[ifr][ks] = *(const f16x8*)&pl[g];
    }

  f32x4 oha[2][2], oma[2][2];
  float psum[2] = {0.f, 0.f};
#pragma unroll
  for (int i = 0; i < 2; ++i)
#pragma unroll
    for (int j = 0; j < 2; ++j)
#pragma unroll
      for (int q = 0; q < 4; ++q) { oha[i][j][q] = 0.0f; oma[i][j][q] = 0.0f; }

  const int vj = tid >> 2;
  const int vs = tid & 3;

  for (int kt = 0; kt < SEQ / 64; ++kt) {
    __syncthreads();
#pragma unroll
    for (int s = 0; s < 2; ++s) {
      int d0 = (vs + s * 4) * 8;
      size_t g = (tok0 + kt * 64 + vj) * (size_t)BQKV + 2 * H_ + hd * HD_ + d0;
      f16x8 vh8 = *(const f16x8*)&ph[g];
      f16x8 vl8 = *(const f16x8*)&pl[g];
#pragma unroll
      for (int u = 0; u < 8; ++u) {
        VtH[swz(d0 + u, vj)] = vh8[u];
        VtL[swz(d0 + u, vj)] = vl8[u];
      }
    }
    __syncthreads();
    f16x8 kfh[2][2], kfl[2][2];
#pragma unroll
    for (int jf = 0; jf < 2; ++jf)
#pragma unroll
      for (int ks = 0; ks < 2; ++ks) {
        size_t g = (tok0 + kt * 64 + wc * 32 + jf * 16 + rr) * (size_t)BQKV + H_ + hd * HD_ + ks * 32 + kg;
        kfh[jf][ks] = *(const f16x8*)&ph[g];
        kfl[jf][ks] = *(const f16x8*)&pl[g];
      }
    // S^T = K.Q^T (3-pass): lane holds keys (lane>>4)*4+q for query rr
    f32x4 sh[2][2], sm2[2][2];   // [jf][ifr]
#pragma unroll
    for (int j = 0; j < 2; ++j)
#pragma unroll
      for (int i = 0; i < 2; ++i)
#pragma unroll
        for (int q = 0; q < 4; ++q) { sh[j][i][q] = 0.0f; sm2[j][i][q] = 0.0f; }
    __builtin_amdgcn_s_setprio(1);
#pragma unroll
    for (int jf = 0; jf < 2; ++jf)
#pragma unroll
      for (int ifr = 0; ifr < 2; ++ifr)
#pragma unroll
        for (int ks = 0; ks < 2; ++ks) {
          sh[jf][ifr]  = __builtin_amdgcn_mfma_f32_16x16x32_f16(kfh[jf][ks], qfh[ifr][ks], sh[jf][ifr], 0, 0, 0);
          sm2[jf][ifr] = __builtin_amdgcn_mfma_f32_16x16x32_f16(kfl[jf][ks], qfh[ifr][ks], sm2[jf][ifr], 0, 0, 0);
          sm2[jf][ifr] = __builtin_amdgcn_mfma_f32_16x16x32_f16(kfh[jf][ks], qfl[ifr][ks], sm2[jf][ifr], 0, 0, 0);
        }
    __builtin_amdgcn_s_setprio(0);
    // softmax numerator; P packed as f16x4 (4 consecutive keys) -> ds_write_b64
#pragma unroll
    for (int ifr = 0; ifr < 2; ++ifr) {
#pragma unroll
      for (int jf = 0; jf < 2; ++jf) {
        f16x4 v4h, v4l;
#pragma unroll
        for (int q = 0; q < 4; ++q) {
          float sval = (sh[jf][ifr][q] + sm2[jf][ifr][q] * (1.0f / 2048.0f)) * 0.125f;
          float p = expf(sval);
          psum[ifr] += p;
          f16 a, b2; split16(p, a, b2);
          v4h[q] = a; v4l[q] = b2;
        }
        int qi = wr * 32 + ifr * 16 + rr;
        int j0 = wc * 32 + jf * 16 + (lane >> 4) * 4;
        *(f16x4*)&PH[swz(qi, j0)] = v4h;
        *(f16x4*)&PL[swz(qi, j0)] = v4l;
      }
    }
    __syncthreads();
    // PV (3-pass): A = P from LDS, B = V^T from LDS
#pragma unroll
    for (int ks = 0; ks < 2; ++ks) {
      f16x8 pfh[2], pfl[2], vfh[2], vfl[2];
#pragma unroll
      for (int ifr = 0; ifr < 2; ++ifr) {
        pfh[ifr] = *(const f16x8*)&PH[swz(wr * 32 + ifr * 16 + rr, ks * 32 + kg)];
        pfl[ifr] = *(const f16x8*)&PL[swz(wr * 32 + ifr * 16 + rr, ks * 32 + kg)];
      }
#pragma unroll
      for (int jf = 0; jf < 2; ++jf) {
        vfh[jf] = *(const f16x8*)&VtH[swz(wc * 32 + jf * 16 + rr, ks * 32 + kg)];
        vfl[jf] = *(const f16x8*)&VtL[swz(wc * 32 + jf * 16 + rr, ks * 32 + kg)];
      }
      __builtin_amdgcn_s_setprio(1);
#pragma unroll
      for (int ifr = 0; ifr < 2; ++ifr)
#pragma unroll
        for (int jf = 0; jf < 2; ++jf) {
          oha[ifr][jf] = __builtin_amdgcn_mfma_f32_16x16x32_f16(pfh[ifr], vfh[jf], oha[ifr][jf], 0, 0, 0);
          oma[ifr][jf] = __builtin_amdgcn_mfma_f32_16x16x32_f16(pfh[ifr], vfl[jf], oma[ifr][jf], 0, 0, 0);
          oma[ifr][jf] = __builtin_amdgcn_mfma_f32_16x16x32_f16(pfl[ifr], vfh[jf], oma[ifr][jf], 0, 0, 0);
        }
      __builtin_amdgcn_s_setprio(0);
    }
  }

  // denominator: reduce over key lane-groups, then across wc via LDS
#pragma unroll
  for (int ifr = 0; ifr < 2; ++ifr) {
    psum[ifr] += __shfl_xor(psum[ifr], 16);
    psum[ifr] += __shfl_xor(psum[ifr], 32);
  }
  if (lane < 16) {
    PS[wc][wr * 32 + lane]      = psum[0];
    PS[wc][wr * 32 + 16 + lane] = psum[1];
  }
  __syncthreads();

#pragma unroll
  for (int ifr = 0; ifr < 2; ++ifr)
#pragma unroll
    for (int jf = 0; jf < 2; ++jf)
#pragma unroll
      for (int q = 0; q < 4; ++q) {
        int i = wr * 32 + ifr * 16 + (lane >> 4) * 4 + q;
        float inv = 1.0f / (PS[0][i] + PS[1][i]);
        float o = (oha[ifr][jf][q] + oma[ifr][jf][q] * (1.0f / 2048.0f)) * inv;
        size_t g = (tok0 + qt * 64 + i) * (size_t)H_ + hd * HD_ + wc * 32 + jf * 16 + rr;
        f16 a, b2; split16(o, a, b2);
        oh[g] = a; ol[g] = b2;
      }
}

// ---------------- x = LN(xin + (p0+p1) + bias)*g + b, + f16 planes ----------------
__global__ __launch_bounds__(256)
void k_ln_res3(const float* __restrict__ xin, const float* __restrict__ part,
               const float* __restrict__ bcol,
               const float* __restrict__ g, const float* __restrict__ bb,
               float* __restrict__ xout, f16* __restrict__ xh, f16* __restrict__ xl) {
  __shared__ float red[8];
  int t = blockIdx.x;
  const float* xr = xin + (size_t)t * H_;
  const float* p0 = part + (size_t)t * H_;
  const float* p1 = part + (size_t)TOK * H_ + (size_t)t * H_;
  float v[3];
#pragma unroll
  for (int j = 0; j < 3; ++j) {
    int hh = threadIdx.x + 256 * j;
    v[j] = xr[hh] + ((p0[hh] + p1[hh]) + bcol[hh]);
  }
  float s = v[0] + v[1] + v[2];
  s = wave_sum(s);
  int w = threadIdx.x >> 6;
  if ((threadIdx.x & 63) == 0) red[w] = s;
  __syncthreads();
  float mu = (red[0] + red[1] + red[2] + red[3]) * (1.0f / 768.0f);
  float q = 0.f;
#pragma unroll
  for (int j = 0; j < 3; ++j) { float d = v[j] - mu; q = fmaf(d, d, q); }
  q = wave_sum(q);
  if ((threadIdx.x & 63) == 0) red[4 + w] = q;
  __syncthreads();
  float var = (red[4] + red[5] + red[6] + red[7]) * (1.0f / 768.0f);
  float rinv = 1.0f / sqrtf(var + 1e-5f);
#pragma unroll
  for (int j = 0; j < 3; ++j) {
    int hh = threadIdx.x + 256 * j;
    float val = fmaf(g[hh], (v[j] - mu) * rinv, bb[hh]);
    size_t idx = (size_t)t * H_ + hh;
    xout[idx] = val;
    f16 a, b; split16(val, a, b);
    xh[idx] = a; xl[idx] = b;
  }
}

// ------- LM: reduce 4 split-K partials + bias -> out0, argmax, histogram -------
__global__ __launch_bounds__(64)
void k_argmax2(const float* __restrict__ part, const float* __restrict__ blm,
               float* __restrict__ out0, int* __restrict__ ix,
               int* __restrict__ counts) {
  int t = blockIdx.x, l = threadIdx.x;
  const size_t S = (size_t)TOK * V_;
  size_t c0 = (size_t)t * V_ + l;
  size_t c1 = c0 + 64;
  float v0 = ((part[c0] + part[S + c0]) + part[2 * S + c0]) + part[3 * S + c0] + blm[l];
  float v1 = ((part[c1] + part[S + c1]) + part[2 * S + c1]) + part[3 * S + c1] + blm[l + 64];
  out0[c0] = v0;
  out0[c1] = v1;
  float best = v0; int bi = l;
  if (v1 > best) { best = v1; bi = 64 + l; }
#pragma unroll
  for (int m = 1; m < 64; m <<= 1) {
    float ov = __shfl_xor(best, m);
    int oi = __shfl_xor(bi, m);
    if (ov > best || (ov == best && oi < bi)) { best = ov; bi = oi; }
  }
  if (l == 0) { ix[t] = bi; atomicAdd(&counts[bi], 1); }
}

// ---------------- route bucketing: scan + chunk table ----------------
__global__ __launch_bounds__(128)
void k_prep(const int* __restrict__ counts, int* __restrict__ offsets,
            int* __restrict__ cursors, int4* __restrict__ chunks,
            int* __restrict__ nchunks) {
  __shared__ int s[128];
  int r = threadIdx.x;
  int c = counts[r];
  s[r] = c; __syncthreads();
  for (int d = 1; d < 128; d <<= 1) {
    int v = (r >= d) ? s[r - d] : 0; __syncthreads();
    s[r] += v; __syncthreads();
  }
  int off = s[r] - c;
  offsets[r] = off;
  cursors[r] = 0;
  int nch = (c + 15) >> 4;
  __syncthreads();
  s[r] = nch; __syncthreads();
  for (int d = 1; d < 128; d <<= 1) {
    int v = (r >= d) ? s[r - d] : 0; __syncthreads();
    s[r] += v; __syncthreads();
  }
  int cb = s[r] - nch;
  for (int u = 0; u < nch; ++u) {
    int rem = c - u * 16;
    chunks[cb + u] = make_int4(r, off + u * 16, rem < 16 ? rem : 16, 0);
  }
  if (r == 127) *nchunks = s[127];
}

__global__ __launch_bounds__(256)
void k_scatter(const int* __restrict__ ix, const int* __restrict__ offsets,
               int* __restrict__ cursors, int* __restrict__ bucket) {
  int t = blockIdx.x * 256 + threadIdx.x;
  int r = ix[t];
  int p = atomicAdd(&cursors[r], 1);
  bucket[offsets[r] + p] = t;
}

// ------- transpose-convert routed W: [r][h][v] fp32 -> [r][v][h] f16 hi/lo -------
__global__ __launch_bounds__(256)
void k_convT(const float* __restrict__ W, f16* __restrict__ wth, f16* __restrict__ wtl) {
  __shared__ float tile[64][65];
  const int r = blockIdx.x, vb = blockIdx.y * 64;
  const int tid = threadIdx.x;
  const int la = tid & 63, wv = tid >> 6;
  for (int ht = 0; ht < H_ / 64; ++ht) {
    int h0 = ht * 64;
#pragma unroll
    for (int i = 0; i < 16; ++i) {
      int row = wv + i * 4;
      tile[row][la] = W[(size_t)r * (H_ * V_) + (size_t)(h0 + row) * V_ + vb + la];
    }
    __syncthreads();
#pragma unroll
    for (int i = 0; i < 16; ++i) {
      int vl = wv + i * 4;
      float w = tile[la][vl];
      f16 a, b; split16(w, a, b);
      size_t o = ((size_t)r * V_ + vb + vl) * H_ + h0 + la;
      wth[o] = a; wtl[o] = b;
    }
    __syncthreads();
  }
}

// ------- MFMA routed head: one chunk (<=16 tokens, 1 route) per block -------
__global__ __launch_bounds__(256)
void k_sublevel3(const f16* __restrict__ xh, const f16* __restrict__ xl,
                 const f16* __restrict__ wth, const f16* __restrict__ wtl,
                 const float* __restrict__ bias, const int* __restrict__ bucket,
                 const int4* __restrict__ chunks, const int* __restrict__ nchunks,
                 float* __restrict__ out) {
  int c = blockIdx.x;
  if (c >= *nchunks) return;
  int4 ch = chunks[c];
  int r = ch.x, ts = ch.y, nt = ch.z;
  __shared__ int toks[16];
  int tid = threadIdx.x;
  if (tid < 16) toks[tid] = bucket[ts + (tid < nt ? tid : 0)];
  __syncthreads();
  const int lane = tid & 63, wid = tid >> 6;
  const int rr = lane & 15, kg = (lane >> 4) * 8;
  const int myTok = toks[rr];
  const size_t abase = (size_t)myTok * H_ + kg;

  f32x4 aH[2], aM[2];
#pragma unroll
  for (int j = 0; j < 2; ++j)
#pragma unroll
    for (int q = 0; q < 4; ++q) { aH[j][q] = 0.0f; aM[j][q] = 0.0f; }

  size_t wb[2];
#pragma unroll
  for (int j = 0; j < 2; ++j)
    wb[j] = ((size_t)r * V_ + wid * 32 + j * 16 + rr) * H_ + kg;

  for (int k0 = 0; k0 < H_; k0 += 32) {
    f16x8 ah = *(const f16x8*)&xh[abase + k0];
    f16x8 al = *(const f16x8*)&xl[abase + k0];
#pragma unroll
    for (int j = 0; j < 2; ++j) {
      f16x8 bh = *(const f16x8*)&wth[wb[j] + k0];
      f16x8 bl = *(const f16x8*)&wtl[wb[j] + k0];
      aH[j] = __builtin_amdgcn_mfma_f32_16x16x32_f16(ah, bh, aH[j], 0, 0, 0);
      aM[j] = __builtin_amdgcn_mfma_f32_16x16x32_f16(ah, bl, aM[j], 0, 0, 0);
      aM[j] = __builtin_amdgcn_mfma_f32_16x16x32_f16(al, bh, aM[j], 0, 0, 0);
    }
  }

  const int r4 = (lane >> 4) * 4, cc = lane & 15;
#pragma unroll
  for (int j = 0; j < 2; ++j) {
#pragma unroll
    for (int q = 0; q < 4; ++q) {
      int row = r4 + q;
      if (row < nt) {
        int col = wid * 32 + j * 16 + cc;
        out[(size_t)toks[row] * V_ + col] =
            aH[j][q] + aM[j][q] * (1.0f / 2048.0f) + bias[(size_t)r * V_ + col];
      }
    }
  }
}

extern "C" void kernel_launch(void* const* d_in, const int* in_sizes, int n_in,
                              void* d_out, int out_size, void* d_ws, size_t ws_size,
                              hipStream_t stream) {
  const int*   lid  = (const int*)d_in[0];
  const int*   sid  = (const int*)d_in[1];
  const float* be   = (const float*)d_in[2];
  const float* se   = (const float*)d_in[3];
  const float* Wqkv = (const float*)d_in[4];
  const float* bqkv = (const float*)d_in[5];
  const float* Wo   = (const float*)d_in[6];
  const float* bo   = (const float*)d_in[7];
  const float* g1   = (const float*)d_in[8];
  const float* b1n  = (const float*)d_in[9];
  const float* W1   = (const float*)d_in[10];
  const float* b1f  = (const float*)d_in[11];
  const float* W2   = (const float*)d_in[12];
  const float* b2f  = (const float*)d_in[13];
  const float* g2   = (const float*)d_in[14];
  const float* b2n  = (const float*)d_in[15];
  const float* Wlm  = (const float*)d_in[16];
  const float* blm  = (const float*)d_in[17];
  const float* Wrt  = (const float*)d_in[18];
  const float* brt  = (const float*)d_in[19];

  char* ws = (char*)d_ws;
  float* x    = (float*)(ws + 0);              // 12,582,912
  f16*   xh   = (f16*)  (ws + 12582912);       //  6,291,456
  f16*   xl   = (f16*)  (ws + 18874368);       //  6,291,456
  f16*   qh   = (f16*)  (ws + 25165824);       // 18,874,368 (midh aliases)
  f16*   ql   = (f16*)  (ws + 44040192);       // 18,874,368 (midl aliases)
  f16*   midh = qh;
  f16*   midl = ql;
  f16*   ath  = (f16*)  (ws + 62914560);       //  6,291,456
  f16*   atl  = (f16*)  (ws + 69206016);       //  6,291,456
  float* bufY = (float*)(ws + 75497472);       // 12,582,912
  // split-K partial regions (aliases of dead buffers at their point of use):
  float* pO   = (float*)(ws + 25165824);       // O-proj partials: 2 x 12.58 MB (qh/ql dead)
  float* pF   = (float*)(ws + 62914560);       // FFN2 partials: 2 x 12.58 MB (ath/atl+bufY dead)
  float* pLM  = bufY;                          // LM partials: 4 x 2.10 MB
  // routed-W transposed planes (qh..atl region, dead after last FFN2/LN2):
  f16*   wth  = (f16*)  (ws + 25165824);       // 25,165,824
  f16*   wtl  = (f16*)  (ws + 50331648);       // 25,165,824 (ends at bufY)
  f16*   wsh  = (f16*)  (ws + 88080384);       //  3,538,944
  f16*   wsl  = (f16*)  (ws + 91619328);       //  3,538,944
  f16*   wlmh = (f16*)  (ws + 95158272);
  f16*   wlml = (f16*)  (ws + 95354880);
  int*   ix   = (int*)  (ws + 95551488);       // 16,384
  int*   counts  = (int*)(ws + 95567872);      // 512
  int*   cursors = (int*)(ws + 95568384);      // 512
  int*   offsets = (int*)(ws + 95568896);      // 1,024
  int4*  chunks  = (int4*)(ws + 95569920);     // 6,144
  int*   nchunks = (int*)(ws + 95576064);      // 256
  int*   bucket  = (int*)(ws + 95576320);      // 16,384
  const size_t need = 95592704;
  if (ws_size < need) return;

  bool big = ws_size >= 95600640ull + 265000000ull;
  f16 *bWqh = nullptr, *bWql = nullptr, *bWoh = nullptr, *bWol = nullptr,
      *bW1h = nullptr, *bW1l = nullptr, *bW2h = nullptr, *bW2l = nullptr;
  if (big) {
    char* p = ws + 95600640;
    bWqh = (f16*)p; p += 42467328;
    bWql = (f16*)p; p += 42467328;
    bWoh = (f16*)p; p += 14155776;
    bWol = (f16*)p; p += 14155776;
    bW1h = (f16*)p; p += 37748736;
    bW1l = (f16*)p; p += 37748736;
    bW2h = (f16*)p; p += 37748736;
    bW2l = (f16*)p; p += 37748736;
    k_convert<<<2048, 256, 0, stream>>>(Wqkv, bWqh, bWql, L_ * BQKV * H_ / 4, 64.f);
    k_convert<<<2048, 256, 0, stream>>>(Wo,   bWoh, bWol, L_ * H_ * H_ / 4, 64.f);
    k_convert<<<2048, 256, 0, stream>>>(W1,   bW1h, bW1l, L_ * F_ * H_ / 4, 64.f);
    k_convert<<<2048, 256, 0, stream>>>(W2,   bW2h, bW2l, L_ * H_ * F_ / 4, 64.f);
  }
  k_convert<<<96, 256, 0, stream>>>(Wlm, wlmh, wlml, V_ * H_ / 4, 64.f);

  float* out0 = (float*)d_out;
  float* out1 = out0 + (size_t)TOK * V_;

  k_embed2<<<TOK, 256, 0, stream>>>(lid, sid, be, se, x, xh, xl, counts);

  for (int l = 0; l < L_; ++l) {
    const float* bqkv_l = bqkv + (size_t)l * BQKV;
    const float* bo_l   = bo   + (size_t)l * H_;
    const float* g1_l   = g1   + (size_t)l * H_;
    const float* b1n_l  = b1n  + (size_t)l * H_;
    const float* b1f_l  = b1f  + (size_t)l * F_;
    const float* b2f_l  = b2f  + (size_t)l * H_;
    const float* g2_l   = g2   + (size_t)l * H_;
    const float* b2n_l  = b2n  + (size_t)l * H_;

    const f16 *wh, *wl2;
    // ---- QKV: planes out ----
    if (big) { wh = bWqh + (size_t)l * BQKV * H_; wl2 = bWql + (size_t)l * BQKV * H_; }
    else {
      k_convert<<<1728, 256, 0, stream>>>(Wqkv + (size_t)l * BQKV * H_, wsh, wsl, BQKV * H_ / 4, 64.f);
      wh = wsh; wl2 = wsl;
    }
    k_gemm5<128, 128, 2, 1><<<dim3(TOK / 128, BQKV / 128, 1), 256, 0, stream>>>(
        xh, xl, wh, wl2, bqkv_l, nullptr, qh, ql, BQKV, H_);
    k_flash_mfma<<<dim3(SEQ / 64, BATCH * NH_), 256, 0, stream>>>(qh, ql, ath, atl);
    // ---- O-proj: split-K2 partials (qh/ql region now dead) ----
    if (big) { wh = bWoh + (size_t)l * H_ * H_; wl2 = bWol + (size_t)l * H_ * H_; }
    else {
      k_convert<<<576, 256, 0, stream>>>(Wo + (size_t)l * H_ * H_, wsh, wsl, H_ * H_ / 4, 64.f);
      wh = wsh; wl2 = wsl;
    }
    k_gemm5<128, 128, 3, 2><<<dim3(TOK / 128, H_ / 128, 2), 256, 0, stream>>>(
        ath, atl, wh, wl2, nullptr, pO, nullptr, nullptr, H_, H_);
    k_ln_res3<<<TOK, 256, 0, stream>>>(x, pO, bo_l, g1_l, b1n_l, x, xh, xl);
    // ---- FFN1 (relu, planes out into mid = qh/ql region) ----
    if (big) { wh = bW1h + (size_t)l * F_ * H_; wl2 = bW1l + (size_t)l * F_ * H_; }
    else {
      k_convert<<<1536, 256, 0, stream>>>(W1 + (size_t)l * F_ * H_, wsh, wsl, F_ * H_ / 4, 64.f);
      wh = wsh; wl2 = wsl;
    }
    k_gemm5<128, 128, 1, 1><<<dim3(TOK / 128, F_ / 128, 1), 256, 0, stream>>>(
        xh, xl, wh, wl2, b1f_l, nullptr, midh, midl, F_, H_);
    // ---- FFN2: split-K2 partials (ath/atl + bufY dead) ----
    if (big) { wh = bW2h + (size_t)l * H_ * F_; wl2 = bW2l + (size_t)l * H_ * F_; }
    else {
      k_convert<<<1536, 256, 0, stream>>>(W2 + (size_t)l * H_ * F_, wsh, wsl, H_ * F_ / 4, 64.f);
      wh = wsh; wl2 = wsl;
    }
    k_gemm5<128, 128, 3, 2><<<dim3(TOK / 128, H_ / 128, 2), 256, 0, stream>>>(
        midh, midl, wh, wl2, nullptr, pF, nullptr, nullptr, H_, F_);
    k_ln_res3<<<TOK, 256, 0, stream>>>(x, pF, b2f_l, g2_l, b2n_l, x, xh, xl);
  }

  // ---- LM head: split-K4 partials into bufY ----
  k_gemm5<64, 64, 3, 4><<<dim3(TOK / 64, V_ / 64, 4), 256, 0, stream>>>(
      xh, xl, wlmh, wlml, nullptr, pLM, nullptr, nullptr, V_, H_);
  // ---- routed-W transpose planes (qh..atl region dead now) ----
  k_convT<<<dim3(V_, 2), 256, 0, stream>>>(Wrt, wth, wtl);
  k_argmax2<<<TOK, 64, 0, stream>>>(pLM, blm, out0, ix, counts);
  k_prep<<<1, 128, 0, stream>>>(counts, offsets, cursors, chunks, nchunks);
  k_scatter<<<TOK / 256, 256, 0, stream>>>(ix, offsets, cursors, bucket);
  k_sublevel3<<<384, 256, 0, stream>>>(xh, xl, wth, wtl, brt, bucket, chunks, nchunks, out1);
}